// Round 11
// baseline (1092.880 us; speedup 1.0000x reference)
//
#include <hip/hip_runtime.h>
#include <math.h>

namespace {

constexpr int NF   = 256;   // n_feature / tokens
constexpr int EH   = 128;   // embedder hidden
constexpr int E    = 64;    // embedded dim
constexpr int H    = 64;    // lstm size
constexpr int SHD  = 256;   // shared hidden
constexpr int SD   = 128;   // shared dim
constexpr int NA   = 257;   // n_action
constexpr int NSHUF = 4;

__device__ __forceinline__ float fsig(float x) {
  return 1.f / (1.f + __expf(-x));
}
__device__ __forceinline__ float ftanh(float x) {
  return 1.f - 2.f / (__expf(2.f * x) + 1.f);
}

// Factored attention (this round): emb = h@We2 + be2 is linear, so
//   logits = h.(We2 qt) (+const, cancels in softmax);  attended = (sum w h)@We2 + be2.
// The 2.1M-FMA emb GEMM disappears; h[256][128] lives in registers
// (2 tok x 32 k per thread). Allocator: (512,2) => 128 VGPR (r9/r10-confirmed).
__global__ __launch_bounds__(512, 2)
void seqnet(
    const float* __restrict__ state, const int* __restrict__ acquired,
    const float* __restrict__ We1, const float* __restrict__ be1,
    const float* __restrict__ We2, const float* __restrict__ be2,
    const float* __restrict__ Wih, const float* __restrict__ Whh,
    const float* __restrict__ bih, const float* __restrict__ bhh,
    const float* __restrict__ Ws1, const float* __restrict__ bs1,
    const float* __restrict__ Ws2, const float* __restrict__ bs2,
    const float* __restrict__ Wp1, const float* __restrict__ bp1,
    const float* __restrict__ Wp2, const float* __restrict__ bp2,
    const float* __restrict__ Wv1, const float* __restrict__ bv1,
    const float* __restrict__ Wv2, const float* __restrict__ bv2,
    float* __restrict__ out)
{
  const int b    = blockIdx.x;
  const int t    = threadIdx.x;   // 0..511
  const int lane = t & 63;
  const int wid  = t >> 6;        // 0..7

  __shared__ int   id_l[NF];
  __shared__ __align__(16) float val_l[NF];
  __shared__ __align__(16) float w_s[NF];          // logits
  __shared__ __align__(16) float r_s[EH];          // r = We2 @ qt
  __shared__ __align__(16) float u_s[EH];          // u = sum_t w_t h_t
  __shared__ __align__(16) float partial[8][EH];   // per-wave u partials
  __shared__ __align__(16) float red_s[512];
  __shared__ __align__(16) float t1_s[SHD];
  __shared__ __align__(16) float sh_s[SD];
  __shared__ __align__(16) float a1_s[SD];
  __shared__ __align__(16) float v1_s[SD];
  __shared__ int   wcnt[4];
  __shared__ float wred[8];
  __shared__ __align__(16) float qt_s[H];
  __shared__ float ct_s[H];
  __shared__ __align__(16) float att_s[E];
  __shared__ float v_scalar;

  // ---------------- phase 0: closed-form "argsort" ----------------
  int ai = 0, pin = 0;
  if (t < NF) {
    id_l[t] = 0; val_l[t] = 0.f;                   // tok >= L defaults
    ai = (acquired[b * NF + t] != 0) ? 1 : 0;
    const unsigned long long mask = __ballot(ai);
    pin = __popcll(mask & ((1ull << lane) - 1ull));
    if (lane == 0) wcnt[wid] = __popcll(mask);     // wid 0..3 here
  }
  if (t < H) { qt_s[t] = 0.f; ct_s[t] = 0.f; att_s[t] = 0.f; }
  __syncthreads();
  const int L = wcnt[0] + wcnt[1] + wcnt[2] + wcnt[3];
  if (t < NF && ai) {
    int pexcl = pin;
    #pragma unroll
    for (int w = 0; w < 4; ++w) if (w < wid) pexcl += wcnt[w];
    const int rank = L - pexcl - 1;                // # acquired with index > t
    id_l[rank]  = t + 1;
    val_l[rank] = state[b * NF + t];
  }
  __syncthreads();

  // ---------------- phase 1: h in registers ----------------
  // thread owns tokens {tg, tg+128}, k-slice [ksf, ksf+32).
  // h[tok][k] = relu(val*We1[0][k] + We1[id][k] + be1[k])
  const int tg   = t >> 2;
  const int ksf  = (t & 3) * 32;
  const int tok0 = tg, tok1 = tg + 128;
  float4 h0[8], h1[8];
  {
    const int   id0 = id_l[tok0]; const float v0 = val_l[tok0];
    const int   id1 = id_l[tok1]; const float v1 = val_l[tok1];
    const float4* __restrict__ g0 = (const float4*)(We1 + id0 * EH + ksf);
    const float4* __restrict__ g1 = (const float4*)(We1 + id1 * EH + ksf);
    const float4* __restrict__ z  = (const float4*)(We1 + ksf);   // row 0
    const float4* __restrict__ bb = (const float4*)(be1 + ksf);
    #pragma unroll
    for (int j = 0; j < 8; ++j) {
      const float4 zz = z[j], dd = bb[j];
      const float4 a = g0[j];
      h0[j].x = fmaxf(fmaf(v0, zz.x, a.x) + dd.x, 0.f);
      h0[j].y = fmaxf(fmaf(v0, zz.y, a.y) + dd.y, 0.f);
      h0[j].z = fmaxf(fmaf(v0, zz.z, a.z) + dd.z, 0.f);
      h0[j].w = fmaxf(fmaf(v0, zz.w, a.w) + dd.w, 0.f);
      const float4 c = g1[j];
      h1[j].x = fmaxf(fmaf(v1, zz.x, c.x) + dd.x, 0.f);
      h1[j].y = fmaxf(fmaf(v1, zz.y, c.y) + dd.y, 0.f);
      h1[j].z = fmaxf(fmaf(v1, zz.z, c.z) + dd.z, 0.f);
      h1[j].w = fmaxf(fmaf(v1, zz.w, c.w) + dd.w, 0.f);
    }
  }

  // ---------------- phase 2: factored attention + LSTM ----------------
  if (L > 0) {
    const float invL = 1.f / (float)L;
    for (int it = 0; it < NSHUF; ++it) {
      float w0, w1;
      if (it == 0) {
        // qt == 0 -> uniform softmax over first L tokens
        w0 = (tok0 < L) ? invL : 0.f;
        w1 = (tok1 < L) ? invL : 0.f;
      } else {
        // r = We2 @ qt (row k of We2 is contiguous)
        if (t < EH) {
          const float* __restrict__ wr = We2 + t * E;
          float x0 = 0.f, x1 = 0.f, x2 = 0.f, x3 = 0.f;
          #pragma unroll
          for (int e = 0; e < E; e += 4) {
            const float4 q = *(const float4*)(qt_s + e);
            x0 = fmaf(wr[e],     q.x, x0);
            x1 = fmaf(wr[e + 1], q.y, x1);
            x2 = fmaf(wr[e + 2], q.z, x2);
            x3 = fmaf(wr[e + 3], q.w, x3);
          }
          r_s[t] = (x0 + x1) + (x2 + x3);
        }
        __syncthreads();
        // logits: l = h . r over this thread's k-slice; reduce 4 lanes
        const float4* __restrict__ rr = (const float4*)(r_s + ksf);
        float l0 = 0.f, l1 = 0.f;
        #pragma unroll
        for (int j = 0; j < 8; ++j) {
          const float4 rj = rr[j];
          l0 = fmaf(h0[j].x, rj.x, fmaf(h0[j].y, rj.y,
               fmaf(h0[j].z, rj.z, fmaf(h0[j].w, rj.w, l0))));
          l1 = fmaf(h1[j].x, rj.x, fmaf(h1[j].y, rj.y,
               fmaf(h1[j].z, rj.z, fmaf(h1[j].w, rj.w, l1))));
        }
        l0 += __shfl_xor(l0, 1); l0 += __shfl_xor(l0, 2);
        l1 += __shfl_xor(l1, 1); l1 += __shfl_xor(l1, 2);
        if ((t & 3) == 0) { w_s[tg] = l0; w_s[tg + 128] = l1; }
        __syncthreads();
        // block softmax stats, computed redundantly per wave (no extra barriers)
        float x0 = (lane       < L) ? w_s[lane]       : -1e30f;
        float x1 = (lane +  64 < L) ? w_s[lane +  64] : -1e30f;
        float x2 = (lane + 128 < L) ? w_s[lane + 128] : -1e30f;
        float x3 = (lane + 192 < L) ? w_s[lane + 192] : -1e30f;
        float m = fmaxf(fmaxf(x0, x1), fmaxf(x2, x3));
        #pragma unroll
        for (int d = 32; d > 0; d >>= 1) m = fmaxf(m, __shfl_xor(m, d));
        float s = __expf(x0 - m) + __expf(x1 - m) + __expf(x2 - m) + __expf(x3 - m);
        #pragma unroll
        for (int d = 32; d > 0; d >>= 1) s += __shfl_xor(s, d);
        const float inv_s = 1.f / s;
        w0 = (tok0 < L) ? __expf(l0 - m) * inv_s : 0.f;
        w1 = (tok1 < L) ? __expf(l1 - m) * inv_s : 0.f;
      }

      // u = sum_t w_t h_t : register partial + 16-lane tree + 8-wave combine
      {
        float4 u[8];
        #pragma unroll
        for (int j = 0; j < 8; ++j) {
          u[j].x = fmaf(w0, h0[j].x, w1 * h1[j].x);
          u[j].y = fmaf(w0, h0[j].y, w1 * h1[j].y);
          u[j].z = fmaf(w0, h0[j].z, w1 * h1[j].z);
          u[j].w = fmaf(w0, h0[j].w, w1 * h1[j].w);
        }
        #pragma unroll
        for (int d = 4; d <= 32; d <<= 1) {
          #pragma unroll
          for (int j = 0; j < 8; ++j) {
            u[j].x += __shfl_xor(u[j].x, d);
            u[j].y += __shfl_xor(u[j].y, d);
            u[j].z += __shfl_xor(u[j].z, d);
            u[j].w += __shfl_xor(u[j].w, d);
          }
        }
        if (lane < 4) {
          #pragma unroll
          for (int j = 0; j < 8; ++j)
            *(float4*)&partial[wid][lane * 32 + j * 4] = u[j];
        }
      }
      __syncthreads();
      if (t < EH) {
        float s0 = 0.f;
        #pragma unroll
        for (int q = 0; q < 8; ++q) s0 += partial[q][t];
        u_s[t] = s0;
      }
      __syncthreads();

      // attended = u @ We2 + be2 (64 threads, coalesced column reads)
      if (t < E) {
        const float* __restrict__ col = We2 + t;     // stride E
        float x0 = 0.f, x1 = 0.f, x2 = 0.f, x3 = 0.f;
        #pragma unroll
        for (int k = 0; k < EH; k += 4) {
          x0 = fmaf(u_s[k],     col[(k)     * E], x0);
          x1 = fmaf(u_s[k + 1], col[(k + 1) * E], x1);
          x2 = fmaf(u_s[k + 2], col[(k + 2) * E], x2);
          x3 = fmaf(u_s[k + 3], col[(k + 3) * E], x3);
        }
        att_s[t] = (x0 + x1) + (x2 + x3) + be2[t];
      }
      __syncthreads();

      // gates: waves 0-3: att@Wih, waves 4-7: qt@Whh (qt=0 at it0 -> 0)
      {
        const int col = t & 255;
        const int hf  = t >> 8;
        const float* __restrict__ W = hf ? Whh : Wih;
        const float* __restrict__ x = hf ? qt_s : att_s;
        float g0 = 0.f, g1 = 0.f, g2 = 0.f, g3 = 0.f;
        #pragma unroll
        for (int e = 0; e < 64; e += 4) {
          const float4 q = *(const float4*)(x + e);
          g0 = fmaf(q.x, W[(e)     * 256 + col], g0);
          g1 = fmaf(q.y, W[(e + 1) * 256 + col], g1);
          g2 = fmaf(q.z, W[(e + 2) * 256 + col], g2);
          g3 = fmaf(q.w, W[(e + 3) * 256 + col], g3);
        }
        red_s[t] = (g0 + g1) + (g2 + g3);
      }
      __syncthreads();
      if (t < H) {   // fused halves-combine + bias + LSTM cell
        const float ig = red_s[t]       + red_s[256 + t]       + bih[t]       + bhh[t];
        const float fg = red_s[64 + t]  + red_s[320 + t]       + bih[64 + t]  + bhh[64 + t];
        const float gg = red_s[128 + t] + red_s[384 + t]       + bih[128 + t] + bhh[128 + t];
        const float og = red_s[192 + t] + red_s[448 + t]       + bih[192 + t] + bhh[192 + t];
        float c = ct_s[t];
        c = fsig(fg) * c + fsig(ig) * ftanh(gg);
        ct_s[t] = c;
        qt_s[t] = fsig(og) * ftanh(c);
      }
      __syncthreads();
    }
  }

  // ---------------- phase 3: DuelingNet (r10 verbatim) ----------------
  {
    const int col = t & 255;
    const int hf  = t >> 8;
    const float* __restrict__ x = hf ? qt_s : att_s;
    const float* __restrict__ W = Ws1 + hf * 64 * SHD;
    float x0 = 0.f, x1 = 0.f, x2 = 0.f, x3 = 0.f;
    #pragma unroll
    for (int k = 0; k < 64; k += 4) {
      const float4 q = *(const float4*)(x + k);
      x0 = fmaf(q.x, W[(k)     * SHD + col], x0);
      x1 = fmaf(q.y, W[(k + 1) * SHD + col], x1);
      x2 = fmaf(q.z, W[(k + 2) * SHD + col], x2);
      x3 = fmaf(q.w, W[(k + 3) * SHD + col], x3);
    }
    red_s[t] = (x0 + x1) + (x2 + x3);
  }
  __syncthreads();
  if (t < SHD) t1_s[t] = fmaxf(red_s[t] + red_s[256 + t] + bs1[t], 0.f);
  __syncthreads();
  {
    const int col = t & 127;
    const int qq  = t >> 7;
    const float* __restrict__ xq = t1_s + qq * 64;
    float x0 = 0.f, x1 = 0.f, x2 = 0.f, x3 = 0.f;
    #pragma unroll
    for (int k = 0; k < 64; k += 4) {
      const float4 q = *(const float4*)(xq + k);
      x0 = fmaf(q.x, Ws2[(qq * 64 + k)     * SD + col], x0);
      x1 = fmaf(q.y, Ws2[(qq * 64 + k + 1) * SD + col], x1);
      x2 = fmaf(q.z, Ws2[(qq * 64 + k + 2) * SD + col], x2);
      x3 = fmaf(q.w, Ws2[(qq * 64 + k + 3) * SD + col], x3);
    }
    red_s[t] = (x0 + x1) + (x2 + x3);
  }
  __syncthreads();
  if (t < SD)
    sh_s[t] = fmaxf((red_s[t] + red_s[128 + t]) + (red_s[256 + t] + red_s[384 + t]) + bs2[t], 0.f);
  __syncthreads();
  {
    const int col  = t & 127;
    const int half = (t >> 7) & 1;
    const int net  = t >> 8;
    const float* __restrict__ W  = (net ? Wv1 : Wp1) + half * 64 * SD;
    const float* __restrict__ xh = sh_s + half * 64;
    float x0 = 0.f, x1 = 0.f, x2 = 0.f, x3 = 0.f;
    #pragma unroll
    for (int k = 0; k < 64; k += 4) {
      const float4 q = *(const float4*)(xh + k);
      x0 = fmaf(q.x, W[(k)     * SD + col], x0);
      x1 = fmaf(q.y, W[(k + 1) * SD + col], x1);
      x2 = fmaf(q.z, W[(k + 2) * SD + col], x2);
      x3 = fmaf(q.w, W[(k + 3) * SD + col], x3);
    }
    red_s[t] = (x0 + x1) + (x2 + x3);
  }
  __syncthreads();
  if (t < SD) {
    a1_s[t] = fmaxf(red_s[t] + red_s[128 + t] + bp1[t], 0.f);
  } else if (t < 2 * SD) {
    const int tt = t - SD;
    v1_s[tt] = fmaxf(red_s[256 + tt] + red_s[384 + tt] + bv1[tt], 0.f);
  }
  __syncthreads();
  if (wid == 7) {
    float vv = fmaf(v1_s[lane], Wv2[lane], v1_s[lane + 64] * Wv2[lane + 64]);
    #pragma unroll
    for (int d = 32; d > 0; d >>= 1) vv += __shfl_xor(vv, d);
    if (lane == 0) v_scalar = vv + bv2[0];
  }
  float adv = 0.f;
  if (t < NA) {
    float x0 = 0.f, x1 = 0.f, x2 = 0.f, x3 = 0.f;
    #pragma unroll
    for (int k = 0; k < SD; k += 4) {
      const float4 a = *(const float4*)(a1_s + k);
      x0 = fmaf(a.x, Wp2[(k)     * NA + t], x0);
      x1 = fmaf(a.y, Wp2[(k + 1) * NA + t], x1);
      x2 = fmaf(a.z, Wp2[(k + 2) * NA + t], x2);
      x3 = fmaf(a.w, Wp2[(k + 3) * NA + t], x3);
    }
    adv = bp2[t] + (x0 + x1) + (x2 + x3);
  }
  float ss = adv;                       // 0 for t >= NA
  #pragma unroll
  for (int d = 32; d > 0; d >>= 1) ss += __shfl_xor(ss, d);
  if (lane == 0) wred[wid] = ss;
  __syncthreads();
  const float mean = ((wred[0] + wred[1]) + (wred[2] + wred[3]) +
                      (wred[4] + wred[5]) + (wred[6] + wred[7])) * (1.f / (float)NA);
  if (t < NA) out[b * NA + t] = v_scalar + adv - mean;
}

}  // namespace

extern "C" void kernel_launch(void* const* d_in, const int* in_sizes, int n_in,
                              void* d_out, int out_size, void* d_ws, size_t ws_size,
                              hipStream_t stream) {
  const float* state    = (const float*)d_in[0];
  const int*   acquired = (const int*)d_in[1];
  const float* We1 = (const float*)d_in[2];
  const float* be1 = (const float*)d_in[3];
  const float* We2 = (const float*)d_in[4];
  const float* be2 = (const float*)d_in[5];
  const float* Wih = (const float*)d_in[6];
  const float* Whh = (const float*)d_in[7];
  const float* bih = (const float*)d_in[8];
  const float* bhh = (const float*)d_in[9];
  const float* Ws1 = (const float*)d_in[10];
  const float* bs1 = (const float*)d_in[11];
  const float* Ws2 = (const float*)d_in[12];
  const float* bs2 = (const float*)d_in[13];
  const float* Wp1 = (const float*)d_in[14];
  const float* bp1 = (const float*)d_in[15];
  const float* Wp2 = (const float*)d_in[16];
  const float* bp2 = (const float*)d_in[17];
  const float* Wv1 = (const float*)d_in[18];
  const float* bv1 = (const float*)d_in[19];
  const float* Wv2 = (const float*)d_in[20];
  const float* bv2 = (const float*)d_in[21];
  float* out = (float*)d_out;

  const int Bn = in_sizes[0] / NF;   // 2048
  hipLaunchKernelGGL(seqnet, dim3(Bn), dim3(512), 0, stream,
                     state, acquired, We1, be1, We2, be2, Wih, Whh, bih, bhh,
                     Ws1, bs1, Ws2, bs2, Wp1, bp1, Wp2, bp2, Wv1, bv1, Wv2, bv2,
                     out);
}